// Round 8
// baseline (299.651 us; speedup 1.0000x reference)
//
#include <hip/hip_runtime.h>
#include <math.h>

#define BS   32
#define A_N  8400
#define G_N  64
#define NC_N 80
#define TK   10
#define DR   48          // delta rows resident in LDS (rank>=DR: rare reload)
#define DSTR 65          // padded row stride

static __device__ __forceinline__ float fdiv(float n, float d) {
    return n * __builtin_amdgcn_rcpf(d);
}
static __device__ __forceinline__ unsigned sortable(float f) {
    unsigned u = __float_as_uint(f);
    return (u & 0x80000000u) ? ~u : (u | 0x80000000u);
}

// ---------------------------------------------------------------------------
// Kernel 1: fused cls-cost + CIoU + gating  ->  cost[b][g][a]
// 256 threads = 64 anchors x 4 class-quarters (phase 1) -> 64 anchor-lanes x
// 4 gt-quarters (phase 2, contiguous 16-gt ranges, unroll 2 for ILP).
// ---------------------------------------------------------------------------
__global__ __launch_bounds__(256)
void k_cost(const float* __restrict__ pred_boxes,   // [BS][A][4]
            const float* __restrict__ gt_boxes,     // [BS][G][4]
            const float* __restrict__ pred_scores,  // [BS][A][NC]
            const int*   __restrict__ gt_labels,    // [BS][G]
            float* __restrict__ cost)               // [BS][G][A]
{
    __shared__ float4 s_box[G_N];          // gx1,gy1,gx2,gy2
    __shared__ float4 s_mid[G_N];          // gsx,gsy,area2,atg
    __shared__ float4 s_ctr[G_N];          // glx,gly,ghx,ghy
    __shared__ float4 s_pb[64];            // pred box per anchor
    __shared__ float4 s_pa[64];            // pcx,pcy,area1,atp
    __shared__ float  s_S[64 * 4];         // partial S, [anchor][q] (b128-readable)
    __shared__ float  s_delta[DR * DSTR];  // [rank][anchor]
    __shared__ int    s_lab[G_N], s_ord[G_N], s_rowk[G_N];
    __shared__ int    s_pres[NC_N], s_rank[NC_N];

    const float EPSF = 1e-9f;
    const float LO = 1e-7f;
    const float HI = (float)(1.0 - 1e-7);
    const int t = threadIdx.x;
    const int b = blockIdx.y;

    if (t < G_N) {
        const float4 gb = ((const float4*)gt_boxes)[b * G_N + t];
        s_box[t] = gb;
        const float sx = gb.x + gb.z, sy = gb.y + gb.w;
        const float w2 = gb.z - gb.x, h2 = (gb.w - gb.y) + EPSF;
        s_mid[t] = make_float4(sx, sy, w2 * h2, atanf(w2 / h2));
        const float cx = sx / 2.0f, cy = sy / 2.0f;
        s_ctr[t] = make_float4(cx - 2.5f, cy - 2.5f, cx + 2.5f, cy + 2.5f);
        s_lab[t] = gt_labels[b * G_N + t];
    }
    __syncthreads();
    if (t < G_N) {               // unique rank by (label, idx) -> sorted order
        const int myl = s_lab[t];
        int rank = 0;
        for (int j = 0; j < G_N; ++j) {
            const int lj = s_lab[j];
            rank += (lj < myl) || (lj == myl && j < t);
        }
        s_ord[rank] = t;
    }
    if (t < NC_N) {              // class presence
        int p = 0;
        for (int j = 0; j < G_N; ++j) p |= (s_lab[j] == t);
        s_pres[t] = p;
    }
    __syncthreads();
    if (t < NC_N) {              // dense rank among present classes
        int r = 0;
        for (int c = 0; c < t; ++c) r += s_pres[c];
        s_rank[t] = s_pres[t] ? r : -1;
    }
    __syncthreads();
    if (t < G_N) s_rowk[t] = s_rank[s_lab[s_ord[t]]];

    // --- phase 1: thread (al, q) handles classes [20q, 20q+20) of anchor al
    {
        const int q  = t & 3;
        const int al = t >> 2;
        const int a  = blockIdx.x * 64 + al;
        if (a < A_N) {
            const float4* p4 =
                (const float4*)(pred_scores + ((size_t)b * A_N + a) * NC_N + q * 20);
            float4 s0 = p4[0], s1 = p4[1], s2 = p4[2], s3 = p4[3], s4 = p4[4];
            s0.x=fminf(fmaxf(s0.x,LO),HI); s0.y=fminf(fmaxf(s0.y,LO),HI);
            s0.z=fminf(fmaxf(s0.z,LO),HI); s0.w=fminf(fmaxf(s0.w,LO),HI);
            s1.x=fminf(fmaxf(s1.x,LO),HI); s1.y=fminf(fmaxf(s1.y,LO),HI);
            s1.z=fminf(fmaxf(s1.z,LO),HI); s1.w=fminf(fmaxf(s1.w,LO),HI);
            s2.x=fminf(fmaxf(s2.x,LO),HI); s2.y=fminf(fmaxf(s2.y,LO),HI);
            s2.z=fminf(fmaxf(s2.z,LO),HI); s2.w=fminf(fmaxf(s2.w,LO),HI);
            s3.x=fminf(fmaxf(s3.x,LO),HI); s3.y=fminf(fmaxf(s3.y,LO),HI);
            s3.z=fminf(fmaxf(s3.z,LO),HI); s3.w=fminf(fmaxf(s3.w,LO),HI);
            s4.x=fminf(fmaxf(s4.x,LO),HI); s4.y=fminf(fmaxf(s4.y,LO),HI);
            s4.z=fminf(fmaxf(s4.z,LO),HI); s4.w=fminf(fmaxf(s4.w,LO),HI);
            float g1 = (1.0f-s0.x); g1*=(1.0f-s0.y); g1*=(1.0f-s0.z); g1*=(1.0f-s0.w);
            g1*=(1.0f-s1.x); g1*=(1.0f-s1.y); g1*=(1.0f-s1.z); g1*=(1.0f-s1.w);
            float g2 = (1.0f-s2.x); g2*=(1.0f-s2.y); g2*=(1.0f-s2.z); g2*=(1.0f-s2.w);
            g2*=(1.0f-s3.x); g2*=(1.0f-s3.y); g2*=(1.0f-s3.z); g2*=(1.0f-s3.w);
            float g3 = (1.0f-s4.x); g3*=(1.0f-s4.y); g3*=(1.0f-s4.z); g3*=(1.0f-s4.w);
            s_S[al * 4 + q] = (logf(g1) + logf(g2)) + logf(g3);
            const float pv[20] = {s0.x,s0.y,s0.z,s0.w, s1.x,s1.y,s1.z,s1.w,
                                  s2.x,s2.y,s2.z,s2.w, s3.x,s3.y,s3.z,s3.w,
                                  s4.x,s4.y,s4.z,s4.w};
            #pragma unroll
            for (int i = 0; i < 20; ++i) {
                const int r = s_rank[q * 20 + i];
                if (r >= 0 && r < DR)
                    s_delta[r * DSTR + al] =
                        logf((1.0f - pv[i]) * __builtin_amdgcn_rcpf(pv[i]));
            }
            if (q == 0) {
                const float4 pb = ((const float4*)pred_boxes)[(size_t)b * A_N + a];
                s_pb[al] = pb;
                const float pcx = (pb.x + pb.z) / 2.0f;
                const float pcy = (pb.y + pb.w) / 2.0f;
                const float w1  = pb.z - pb.x;
                const float h1  = (pb.w - pb.y) + EPSF;
                s_pa[al] = make_float4(pcx, pcy, w1 * h1, atanf(w1 / h1));
            }
        }
    }
    __syncthreads();

    // --- phase 2: wave gs emits sorted positions [gs*16, gs*16+16)
    const int la = t & 63;
    const int gs = t >> 6;
    const int a  = blockIdx.x * 64 + la;
    if (a >= A_N) return;

    const float4 pb = s_pb[la];
    const float4 pa = s_pa[la];   // pcx,pcy,area1,atp
    const float4 Sq = ((const float4*)s_S)[la];
    const float S = -(((Sq.x + Sq.y) + Sq.z) + Sq.w);
    const float KPI = (float)(4.0 / (M_PI * M_PI));
    const float* prow = pred_scores + ((size_t)b * A_N + a) * NC_N;  // fallback only
    float* crow = cost + (size_t)b * G_N * A_N + a;
    const float pcx = pa.x, pcy = pa.y, area1 = pa.z, atp = pa.w;

    #pragma unroll 2
    for (int k = gs * 16; k < gs * 16 + 16; ++k) {
        const int g = s_ord[k];           // uniform per wave
        const int r = s_rowk[k];          // uniform
        float delta;
        if (r < DR) {
            delta = s_delta[r * DSTR + la];
        } else {
            const float pc = fminf(fmaxf(prow[s_lab[g]], LO), HI);
            delta = logf((1.0f - pc) * __builtin_amdgcn_rcpf(pc));
        }
        const float Sd = S + delta;
        const float4 gb = s_box[g];
        const float4 gm = s_mid[g];
        const float4 gc = s_ctr[g];

        const bool inb  = (pcx > gb.x) && (pcy > gb.y) && (gb.z > pcx) && (gb.w > pcy);
        const bool inc  = (pcx > gc.x) && (pcy > gc.y) && (gc.z > pcx) && (gc.w > pcy);
        const bool both = inb && inc;

        const float iw    = fmaxf(fminf(pb.z, gb.z) - fmaxf(pb.x, gb.x), 0.0f);
        const float ih    = fmaxf(fminf(pb.w, gb.w) - fmaxf(pb.y, gb.y), 0.0f);
        const float inter = iw * ih;
        const float uni   = ((area1 + gm.z) - inter) + EPSF;
        const float iou   = fdiv(inter, uni);
        const float cw    = fmaxf(pb.z, gb.z) - fminf(pb.x, gb.x);
        const float ch    = fmaxf(pb.w, gb.w) - fminf(pb.y, gb.y);
        const float c2    = ((cw * cw) + (ch * ch)) + EPSF;
        const float dx    = (gm.x - pb.x) - pb.z;
        const float dy    = (gm.y - pb.y) - pb.w;
        const float d2    = ((dx * dx) + (dy * dy)) / 4.0f;
        const float dif   = gm.w - atp;
        const float v     = KPI * (dif * dif);
        const float alpha = fdiv(v, (v - iou) + 1.0f);
        const float ciou  = iou - (fdiv(d2, c2) + v * alpha);

        const float cst   = (Sd + 3.0f * ciou) + (both ? 0.0f : 100000.0f);
        crow[(size_t)g * A_N] = cst;
    }
}

// ---------------------------------------------------------------------------
// slot init: 0xFF-fill slot array (2.15 MB)
// ---------------------------------------------------------------------------
__global__ __launch_bounds__(256)
void k_init(uint4* __restrict__ slt, long ns4)
{
    const long stride = (long)gridDim.x * 256;
    const uint4 m4 = make_uint4(~0u, ~0u, ~0u, ~0u);
    for (long i = (long)blockIdx.x * 256 + threadIdx.x; i < ns4; i += stride)
        slt[i] = m4;
}

// ---------------------------------------------------------------------------
// Kernel 2: top-10 smallest per (b,g) row + fused slot atomicMin scatter.
// key = (sortable(cost) << 14) | a.  slot key = (sortable << 6) | g.
// ---------------------------------------------------------------------------
__global__ __launch_bounds__(256)
void k_topk(const float* __restrict__ cost,
            const unsigned char* __restrict__ mask_gt,
            int* __restrict__ topk,
            unsigned long long* __restrict__ slot)   // [BS][A_N]
{
    __shared__ unsigned long long s_w[4][TK];

    const int bg   = blockIdx.x;            // bg = b*G_N + g
    const int t    = threadIdx.x;
    const int lane = t & 63;
    const int wid  = t >> 6;
    const float* row = cost + (size_t)bg * A_N;
    const unsigned long long UMAX = ~0ull;

    unsigned long long v[TK];
    #pragma unroll
    for (int j = 0; j < TK; ++j) v[j] = UMAX;

    auto consider = [&](float c, int idx) {
        const unsigned long long key =
            ((unsigned long long)sortable(c) << 14) | (unsigned)idx;
        if (key < v[TK - 1]) {
            v[TK - 1] = key;
            #pragma unroll
            for (int j = TK - 2; j >= 0; --j) {
                const bool sw = v[j + 1] < v[j];
                const unsigned long long tv = v[j];
                v[j]     = sw ? v[j + 1] : v[j];
                v[j + 1] = sw ? tv : v[j + 1];
            }
        }
    };

    const float4* row4 = (const float4*)row;
    const int NV = A_N / 4;
    float4 cur = make_float4(0.f, 0.f, 0.f, 0.f);
    if (t < NV) cur = row4[t];
    for (int i = t; i < NV; i += 256) {
        const int i2 = i + 256;
        float4 nxt = make_float4(0.f, 0.f, 0.f, 0.f);
        if (i2 < NV) nxt = row4[i2];
        const int base = i * 4;
        consider(cur.x, base);
        consider(cur.y, base + 1);
        consider(cur.z, base + 2);
        consider(cur.w, base + 3);
        cur = nxt;
    }

    #pragma unroll
    for (int r = 0; r < TK; ++r) {
        unsigned long long bv = v[0];
        #pragma unroll
        for (int off = 1; off < 64; off <<= 1) {
            const unsigned long long ov = __shfl_xor(bv, off, 64);
            bv = (ov < bv) ? ov : bv;
        }
        if (lane == 0) s_w[wid][r] = bv;
        if (v[0] == bv) {
            #pragma unroll
            for (int j = 0; j < TK - 1; ++j) v[j] = v[j + 1];
            v[TK - 1] = UMAX;
        }
    }
    __syncthreads();

    if (wid == 0) {
        const int b = bg >> 6, g = bg & 63;
        const int msk = (int)mask_gt[bg];
        unsigned long long cv = UMAX;
        if (lane < 4 * TK) cv = s_w[lane / TK][lane % TK];
        #pragma unroll
        for (int r = 0; r < TK; ++r) {
            unsigned long long bv = cv;
            #pragma unroll
            for (int off = 1; off < 64; off <<= 1) {
                const unsigned long long ov = __shfl_xor(bv, off, 64);
                bv = (ov < bv) ? ov : bv;
            }
            if (lane == 0) {
                const int a = (int)(bv & 16383ull);
                topk[bg * TK + r] = a;
                if (msk) {
                    const unsigned long long key = ((bv >> 14) << 6) | (unsigned)g;
                    atomicMin(&slot[(size_t)b * A_N + a], key);
                }
            }
            if (cv == bv) cv = UMAX;
        }
    }
}

// ---------------------------------------------------------------------------
// Dense final from slot: final[b,g,a] = (slot[b][a]!=UMAX && (slot&63)==g).
// Thread owns 4 consecutive anchors; one float4 store per g (coalesced).
// ---------------------------------------------------------------------------
__global__ __launch_bounds__(256)
void k_fin(const unsigned long long* __restrict__ slot,
           float* __restrict__ final_out)            // [BS][G][A]
{
    const int i = blockIdx.x * 256 + threadIdx.x;    // float4 index in [0, 2100)
    const int b = blockIdx.y;
    if (i >= A_N / 4) return;

    const unsigned long long* sp = slot + (size_t)b * A_N + i * 4;
    int w0 = -1, w1 = -1, w2 = -1, w3 = -1;
    {
        const unsigned long long s0 = sp[0], s1 = sp[1], s2 = sp[2], s3 = sp[3];
        if (s0 != ~0ull) w0 = (int)(s0 & 63ull);
        if (s1 != ~0ull) w1 = (int)(s1 & 63ull);
        if (s2 != ~0ull) w2 = (int)(s2 & 63ull);
        if (s3 != ~0ull) w3 = (int)(s3 & 63ull);
    }
    float4* fp = (float4*)(final_out + (size_t)b * G_N * A_N) + i;
    for (int g = 0; g < G_N; ++g) {
        const float4 o = make_float4(w0 == g ? 1.0f : 0.0f,
                                     w1 == g ? 1.0f : 0.0f,
                                     w2 == g ? 1.0f : 0.0f,
                                     w3 == g ? 1.0f : 0.0f);
        fp[(size_t)g * (A_N / 4)] = o;
    }
}

// ---------------------------------------------------------------------------
// Fallback dense final (used only if ws_size too small for slot array)
// ---------------------------------------------------------------------------
__global__ __launch_bounds__(256)
void k_final(const float* __restrict__ cost,
             const int*   __restrict__ topk,
             const unsigned char* __restrict__ mask_gt,
             float* __restrict__ final_out)
{
    __shared__ int s_top[G_N * TK];
    __shared__ int s_mask[G_N];

    const int t = threadIdx.x;
    const int b = blockIdx.y;
    const int a = blockIdx.x * 256 + t;

    for (int k = t; k < G_N * TK; k += 256) s_top[k] = topk[b * G_N * TK + k];
    if (t < G_N) s_mask[t] = (int)mask_gt[b * G_N + t];
    __syncthreads();
    if (a >= A_N) return;

    unsigned long long member = 0ull;
    int cnt = 0;
    float best = __builtin_inff();
    int bestg = 0;
    for (int g = 0; g < G_N; ++g) {
        bool m = false;
        if (s_mask[g]) {
            #pragma unroll
            for (int j = 0; j < TK; ++j) m = m || (s_top[g * TK + j] == a);
        }
        if (m) {
            member |= (1ull << g);
            ++cnt;
            const float c = cost[((size_t)b * G_N + g) * A_N + a];
            if (c < best) { best = c; bestg = g; }
        }
    }
    const bool ovl = cnt > 1;
    float* frow = final_out + (size_t)b * G_N * A_N + a;
    for (int g = 0; g < G_N; ++g) {
        const bool f = ovl ? (g == bestg) : (((member >> g) & 1ull) != 0ull);
        frow[(size_t)g * A_N] = f ? 1.0f : 0.0f;
    }
}

// ---------------------------------------------------------------------------
extern "C" void kernel_launch(void* const* d_in, const int* in_sizes, int n_in,
                              void* d_out, int out_size, void* d_ws, size_t ws_size,
                              hipStream_t stream)
{
    const float* pred_boxes  = (const float*)d_in[0];
    const float* gt_boxes    = (const float*)d_in[1];
    const unsigned char* mask_gt = (const unsigned char*)d_in[2];
    const float* pred_scores = (const float*)d_in[3];
    const int*   gt_labels   = (const int*)d_in[4];

    float* out_final = (float*)d_out;
    float* out_cost  = out_final + (size_t)BS * G_N * A_N;

    const size_t slot_bytes = (size_t)BS * A_N * sizeof(unsigned long long);
    const size_t topk_bytes = (size_t)BS * G_N * TK * sizeof(int);
    unsigned long long* slot = (unsigned long long*)d_ws;
    int* topk_ws = (int*)((char*)d_ws + slot_bytes);
    const bool sparse_ok = ws_size >= slot_bytes + topk_bytes;
    if (!sparse_ok) topk_ws = (int*)d_ws;

    if (sparse_ok) {
        const long ns4 = (long)BS * A_N / 2;   // u64 pairs as uint4
        k_init<<<dim3(132), 256, 0, stream>>>((uint4*)slot, ns4);
    }

    k_cost <<<dim3((A_N + 63) / 64, BS), 256, 0, stream>>>(
        pred_boxes, gt_boxes, pred_scores, gt_labels, out_cost);

    if (sparse_ok) {
        k_topk<<<dim3(BS * G_N), 256, 0, stream>>>(out_cost, mask_gt, topk_ws, slot);
        k_fin <<<dim3((A_N / 4 + 255) / 256, BS), 256, 0, stream>>>(slot, out_final);
    } else {
        k_topk<<<dim3(BS * G_N), 256, 0, stream>>>(out_cost, mask_gt, topk_ws, slot);
        k_final<<<dim3((A_N + 255) / 256, BS), 256, 0, stream>>>(
            out_cost, topk_ws, mask_gt, out_final);
    }
}

// Round 9
// 290.501 us; speedup vs baseline: 1.0315x; 1.0315x over previous
//
#include <hip/hip_runtime.h>
#include <math.h>

#define BS   32
#define A_N  8400
#define G_N  64
#define NC_N 80
#define TK   10
#define DR   48          // delta rows resident in LDS (rank>=DR: rare reload)
#define DSTR 65          // padded row stride

static __device__ __forceinline__ float fdiv(float n, float d) {
    return n * __builtin_amdgcn_rcpf(d);
}
static __device__ __forceinline__ unsigned sortable(float f) {
    unsigned u = __float_as_uint(f);
    return (u & 0x80000000u) ? ~u : (u | 0x80000000u);
}

// ---------------------------------------------------------------------------
// k_setup: per-batch gt tables, computed ONCE per b (they were previously
// recomputed by all 132 blocks of each b inside k_cost).
//   tb_box:  gt box              tb_mid: gsx,gsy,area2,atg
//   tb_ctr:  center +-2.5 gates  tb_ord: gts sorted by (label,idx)
//   tb_rowk: delta-row rank per sorted position  tb_lab: raw labels
//   tb_rank: class -> dense rank among present classes (or -1)
// ---------------------------------------------------------------------------
__global__ __launch_bounds__(128)
void k_setup(const float* __restrict__ gt_boxes,
             const int*   __restrict__ gt_labels,
             float4* __restrict__ tb_box, float4* __restrict__ tb_mid,
             float4* __restrict__ tb_ctr,
             int* __restrict__ tb_ord, int* __restrict__ tb_rowk,
             int* __restrict__ tb_lab, int* __restrict__ tb_rank)
{
    __shared__ int s_lab[G_N], s_ord[G_N], s_pres[NC_N], s_rank[NC_N];
    const int b = blockIdx.x;
    const int t = threadIdx.x;

    if (t < G_N) {
        const float4 gb = ((const float4*)gt_boxes)[b * G_N + t];
        tb_box[b * G_N + t] = gb;
        const float sx = gb.x + gb.z, sy = gb.y + gb.w;
        const float w2 = gb.z - gb.x, h2 = (gb.w - gb.y) + 1e-9f;
        tb_mid[b * G_N + t] = make_float4(sx, sy, w2 * h2, atanf(w2 / h2));
        const float cx = sx / 2.0f, cy = sy / 2.0f;
        tb_ctr[b * G_N + t] = make_float4(cx - 2.5f, cy - 2.5f, cx + 2.5f, cy + 2.5f);
        const int l = gt_labels[b * G_N + t];
        s_lab[t] = l;
        tb_lab[b * G_N + t] = l;
    }
    __syncthreads();
    if (t < G_N) {               // unique rank by (label, idx)
        const int myl = s_lab[t];
        int rank = 0;
        for (int j = 0; j < G_N; ++j) {
            const int lj = s_lab[j];
            rank += (lj < myl) || (lj == myl && j < t);
        }
        s_ord[rank] = t;
    }
    if (t < NC_N) {
        int p = 0;
        for (int j = 0; j < G_N; ++j) p |= (s_lab[j] == t);
        s_pres[t] = p;
    }
    __syncthreads();
    if (t < NC_N) {
        int r = 0;
        for (int c = 0; c < t; ++c) r += s_pres[c];
        const int rr = s_pres[t] ? r : -1;
        s_rank[t] = rr;
        tb_rank[b * NC_N + t] = rr;
    }
    __syncthreads();
    if (t < G_N) {
        tb_ord[b * G_N + t]  = s_ord[t];
        tb_rowk[b * G_N + t] = s_rank[s_lab[s_ord[t]]];
    }
}

// ---------------------------------------------------------------------------
// Kernel 1: fused cls-cost + CIoU + gating  ->  cost[b][g][a]
// 256 threads = 64 anchors x 4 class-quarters (phase 1) -> 64 anchor-lanes x
// 4 gt-quarters (phase 2). Preamble = table loads only. Native __logf.
// ---------------------------------------------------------------------------
__global__ __launch_bounds__(256)
void k_cost(const float* __restrict__ pred_boxes,   // [BS][A][4]
            const float* __restrict__ pred_scores,  // [BS][A][NC]
            const float4* __restrict__ tb_box, const float4* __restrict__ tb_mid,
            const float4* __restrict__ tb_ctr,
            const int* __restrict__ tb_ord, const int* __restrict__ tb_rowk,
            const int* __restrict__ tb_lab, const int* __restrict__ tb_rank,
            float* __restrict__ cost)               // [BS][G][A]
{
    __shared__ float4 s_box[G_N];          // gx1,gy1,gx2,gy2
    __shared__ float4 s_mid[G_N];          // gsx,gsy,area2,atg
    __shared__ float4 s_ctr[G_N];          // glx,gly,ghx,ghy
    __shared__ float4 s_pb[64];            // pred box per anchor
    __shared__ float4 s_pa[64];            // pcx,pcy,area1,atp
    __shared__ float  s_S[64 * 4];         // partial S, [anchor][q]
    __shared__ float  s_delta[DR * DSTR];  // [rank][anchor]
    __shared__ int    s_lab[G_N], s_ord[G_N], s_rowk[G_N];
    __shared__ int    s_rank[NC_N];

    const float EPSF = 1e-9f;
    const float LO = 1e-7f;
    const float HI = (float)(1.0 - 1e-7);
    const int t = threadIdx.x;
    const int b = blockIdx.y;

    // --- preamble: pure table loads
    if (t < 64) {
        s_box[t]  = tb_box[b * 64 + t];
        s_ord[t]  = tb_ord[b * 64 + t];
        s_rowk[t] = tb_rowk[b * 64 + t];
        s_lab[t]  = tb_lab[b * 64 + t];
    } else if (t < 128) {
        s_mid[t - 64] = tb_mid[b * 64 + (t - 64)];
    } else if (t < 192) {
        s_ctr[t - 128] = tb_ctr[b * 64 + (t - 128)];
    }
    if (t >= 176) s_rank[t - 176] = tb_rank[b * NC_N + (t - 176)];
    __syncthreads();

    // --- phase 1: thread (al, q) handles classes [20q, 20q+20) of anchor al
    {
        const int q  = t & 3;
        const int al = t >> 2;
        const int a  = blockIdx.x * 64 + al;
        if (a < A_N) {
            const float4* p4 =
                (const float4*)(pred_scores + ((size_t)b * A_N + a) * NC_N + q * 20);
            float4 s0 = p4[0], s1 = p4[1], s2 = p4[2], s3 = p4[3], s4 = p4[4];
            s0.x=fminf(fmaxf(s0.x,LO),HI); s0.y=fminf(fmaxf(s0.y,LO),HI);
            s0.z=fminf(fmaxf(s0.z,LO),HI); s0.w=fminf(fmaxf(s0.w,LO),HI);
            s1.x=fminf(fmaxf(s1.x,LO),HI); s1.y=fminf(fmaxf(s1.y,LO),HI);
            s1.z=fminf(fmaxf(s1.z,LO),HI); s1.w=fminf(fmaxf(s1.w,LO),HI);
            s2.x=fminf(fmaxf(s2.x,LO),HI); s2.y=fminf(fmaxf(s2.y,LO),HI);
            s2.z=fminf(fmaxf(s2.z,LO),HI); s2.w=fminf(fmaxf(s2.w,LO),HI);
            s3.x=fminf(fmaxf(s3.x,LO),HI); s3.y=fminf(fmaxf(s3.y,LO),HI);
            s3.z=fminf(fmaxf(s3.z,LO),HI); s3.w=fminf(fmaxf(s3.w,LO),HI);
            s4.x=fminf(fmaxf(s4.x,LO),HI); s4.y=fminf(fmaxf(s4.y,LO),HI);
            s4.z=fminf(fmaxf(s4.z,LO),HI); s4.w=fminf(fmaxf(s4.w,LO),HI);
            float g1 = (1.0f-s0.x); g1*=(1.0f-s0.y); g1*=(1.0f-s0.z); g1*=(1.0f-s0.w);
            g1*=(1.0f-s1.x); g1*=(1.0f-s1.y); g1*=(1.0f-s1.z); g1*=(1.0f-s1.w);
            float g2 = (1.0f-s2.x); g2*=(1.0f-s2.y); g2*=(1.0f-s2.z); g2*=(1.0f-s2.w);
            g2*=(1.0f-s3.x); g2*=(1.0f-s3.y); g2*=(1.0f-s3.z); g2*=(1.0f-s3.w);
            float g3 = (1.0f-s4.x); g3*=(1.0f-s4.y); g3*=(1.0f-s4.z); g3*=(1.0f-s4.w);
            s_S[al * 4 + q] = (__logf(g1) + __logf(g2)) + __logf(g3);
            const float pv[20] = {s0.x,s0.y,s0.z,s0.w, s1.x,s1.y,s1.z,s1.w,
                                  s2.x,s2.y,s2.z,s2.w, s3.x,s3.y,s3.z,s3.w,
                                  s4.x,s4.y,s4.z,s4.w};
            #pragma unroll
            for (int i = 0; i < 20; ++i) {
                const int r = s_rank[q * 20 + i];
                if (r >= 0 && r < DR)
                    s_delta[r * DSTR + al] =
                        __logf((1.0f - pv[i]) * __builtin_amdgcn_rcpf(pv[i]));
            }
            if (q == 0) {
                const float4 pb = ((const float4*)pred_boxes)[(size_t)b * A_N + a];
                s_pb[al] = pb;
                const float pcx = (pb.x + pb.z) / 2.0f;
                const float pcy = (pb.y + pb.w) / 2.0f;
                const float w1  = pb.z - pb.x;
                const float h1  = (pb.w - pb.y) + EPSF;
                s_pa[al] = make_float4(pcx, pcy, w1 * h1, atanf(w1 / h1));
            }
        }
    }
    __syncthreads();

    // --- phase 2: wave gs emits sorted positions [gs*16, gs*16+16)
    const int la = t & 63;
    const int gs = t >> 6;
    const int a  = blockIdx.x * 64 + la;
    if (a >= A_N) return;

    const float4 pb = s_pb[la];
    const float4 pa = s_pa[la];   // pcx,pcy,area1,atp
    const float4 Sq = ((const float4*)s_S)[la];
    const float S = -(((Sq.x + Sq.y) + Sq.z) + Sq.w);
    const float KPI = (float)(4.0 / (M_PI * M_PI));
    const float* prow = pred_scores + ((size_t)b * A_N + a) * NC_N;  // fallback only
    float* crow = cost + (size_t)b * G_N * A_N + a;
    const float pcx = pa.x, pcy = pa.y, area1 = pa.z, atp = pa.w;

    #pragma unroll 4
    for (int k = gs * 16; k < gs * 16 + 16; ++k) {
        const int g = s_ord[k];           // uniform per wave
        const int r = s_rowk[k];          // uniform
        float delta;
        if (r < DR) {
            delta = s_delta[r * DSTR + la];
        } else {
            const float pc = fminf(fmaxf(prow[s_lab[g]], LO), HI);
            delta = __logf((1.0f - pc) * __builtin_amdgcn_rcpf(pc));
        }
        const float Sd = S + delta;
        const float4 gb = s_box[g];
        const float4 gm = s_mid[g];
        const float4 gc = s_ctr[g];

        const bool inb  = (pcx > gb.x) && (pcy > gb.y) && (gb.z > pcx) && (gb.w > pcy);
        const bool inc  = (pcx > gc.x) && (pcy > gc.y) && (gc.z > pcx) && (gc.w > pcy);
        const bool both = inb && inc;

        const float iw    = fmaxf(fminf(pb.z, gb.z) - fmaxf(pb.x, gb.x), 0.0f);
        const float ih    = fmaxf(fminf(pb.w, gb.w) - fmaxf(pb.y, gb.y), 0.0f);
        const float inter = iw * ih;
        const float uni   = ((area1 + gm.z) - inter) + EPSF;
        const float iou   = fdiv(inter, uni);
        const float cw    = fmaxf(pb.z, gb.z) - fminf(pb.x, gb.x);
        const float ch    = fmaxf(pb.w, gb.w) - fminf(pb.y, gb.y);
        const float c2    = ((cw * cw) + (ch * ch)) + EPSF;
        const float dx    = (gm.x - pb.x) - pb.z;
        const float dy    = (gm.y - pb.y) - pb.w;
        const float d2    = ((dx * dx) + (dy * dy)) / 4.0f;
        const float dif   = gm.w - atp;
        const float v     = KPI * (dif * dif);
        const float alpha = fdiv(v, (v - iou) + 1.0f);
        const float ciou  = iou - (fdiv(d2, c2) + v * alpha);

        const float cst   = (Sd + 3.0f * ciou) + (both ? 0.0f : 100000.0f);
        crow[(size_t)g * A_N] = cst;
    }
}

// ---------------------------------------------------------------------------
// slot init: 0xFF-fill slot array (2.15 MB)
// ---------------------------------------------------------------------------
__global__ __launch_bounds__(256)
void k_init(uint4* __restrict__ slt, long ns4)
{
    const long stride = (long)gridDim.x * 256;
    const uint4 m4 = make_uint4(~0u, ~0u, ~0u, ~0u);
    for (long i = (long)blockIdx.x * 256 + threadIdx.x; i < ns4; i += stride)
        slt[i] = m4;
}

// ---------------------------------------------------------------------------
// Kernel 2: top-10 smallest per (b,g) row + fused slot atomicMin scatter.
// ---------------------------------------------------------------------------
__global__ __launch_bounds__(256)
void k_topk(const float* __restrict__ cost,
            const unsigned char* __restrict__ mask_gt,
            int* __restrict__ topk,
            unsigned long long* __restrict__ slot)   // [BS][A_N]
{
    __shared__ unsigned long long s_w[4][TK];

    const int bg   = blockIdx.x;            // bg = b*G_N + g
    const int t    = threadIdx.x;
    const int lane = t & 63;
    const int wid  = t >> 6;
    const float* row = cost + (size_t)bg * A_N;
    const unsigned long long UMAX = ~0ull;

    unsigned long long v[TK];
    #pragma unroll
    for (int j = 0; j < TK; ++j) v[j] = UMAX;

    auto consider = [&](float c, int idx) {
        const unsigned long long key =
            ((unsigned long long)sortable(c) << 14) | (unsigned)idx;
        if (key < v[TK - 1]) {
            v[TK - 1] = key;
            #pragma unroll
            for (int j = TK - 2; j >= 0; --j) {
                const bool sw = v[j + 1] < v[j];
                const unsigned long long tv = v[j];
                v[j]     = sw ? v[j + 1] : v[j];
                v[j + 1] = sw ? tv : v[j + 1];
            }
        }
    };

    const float4* row4 = (const float4*)row;
    const int NV = A_N / 4;
    float4 cur = make_float4(0.f, 0.f, 0.f, 0.f);
    if (t < NV) cur = row4[t];
    for (int i = t; i < NV; i += 256) {
        const int i2 = i + 256;
        float4 nxt = make_float4(0.f, 0.f, 0.f, 0.f);
        if (i2 < NV) nxt = row4[i2];
        const int base = i * 4;
        consider(cur.x, base);
        consider(cur.y, base + 1);
        consider(cur.z, base + 2);
        consider(cur.w, base + 3);
        cur = nxt;
    }

    #pragma unroll
    for (int r = 0; r < TK; ++r) {
        unsigned long long bv = v[0];
        #pragma unroll
        for (int off = 1; off < 64; off <<= 1) {
            const unsigned long long ov = __shfl_xor(bv, off, 64);
            bv = (ov < bv) ? ov : bv;
        }
        if (lane == 0) s_w[wid][r] = bv;
        if (v[0] == bv) {
            #pragma unroll
            for (int j = 0; j < TK - 1; ++j) v[j] = v[j + 1];
            v[TK - 1] = UMAX;
        }
    }
    __syncthreads();

    if (wid == 0) {
        const int b = bg >> 6, g = bg & 63;
        const int msk = (int)mask_gt[bg];
        unsigned long long cv = UMAX;
        if (lane < 4 * TK) cv = s_w[lane / TK][lane % TK];
        #pragma unroll
        for (int r = 0; r < TK; ++r) {
            unsigned long long bv = cv;
            #pragma unroll
            for (int off = 1; off < 64; off <<= 1) {
                const unsigned long long ov = __shfl_xor(bv, off, 64);
                bv = (ov < bv) ? ov : bv;
            }
            if (lane == 0) {
                const int a = (int)(bv & 16383ull);
                topk[bg * TK + r] = a;
                if (msk) {
                    const unsigned long long key = ((bv >> 14) << 6) | (unsigned)g;
                    atomicMin(&slot[(size_t)b * A_N + a], key);
                }
            }
            if (cv == bv) cv = UMAX;
        }
    }
}

// ---------------------------------------------------------------------------
// Dense final from slot: final[b,g,a] = (slot[b][a]!=UMAX && (slot&63)==g).
// ---------------------------------------------------------------------------
__global__ __launch_bounds__(256)
void k_fin(const unsigned long long* __restrict__ slot,
           float* __restrict__ final_out)            // [BS][G][A]
{
    const int i = blockIdx.x * 256 + threadIdx.x;    // float4 index in [0, 2100)
    const int b = blockIdx.y;
    if (i >= A_N / 4) return;

    const unsigned long long* sp = slot + (size_t)b * A_N + i * 4;
    int w0 = -1, w1 = -1, w2 = -1, w3 = -1;
    {
        const unsigned long long s0 = sp[0], s1 = sp[1], s2 = sp[2], s3 = sp[3];
        if (s0 != ~0ull) w0 = (int)(s0 & 63ull);
        if (s1 != ~0ull) w1 = (int)(s1 & 63ull);
        if (s2 != ~0ull) w2 = (int)(s2 & 63ull);
        if (s3 != ~0ull) w3 = (int)(s3 & 63ull);
    }
    float4* fp = (float4*)(final_out + (size_t)b * G_N * A_N) + i;
    for (int g = 0; g < G_N; ++g) {
        const float4 o = make_float4(w0 == g ? 1.0f : 0.0f,
                                     w1 == g ? 1.0f : 0.0f,
                                     w2 == g ? 1.0f : 0.0f,
                                     w3 == g ? 1.0f : 0.0f);
        fp[(size_t)g * (A_N / 4)] = o;
    }
}

// ---------------------------------------------------------------------------
extern "C" void kernel_launch(void* const* d_in, const int* in_sizes, int n_in,
                              void* d_out, int out_size, void* d_ws, size_t ws_size,
                              hipStream_t stream)
{
    const float* pred_boxes  = (const float*)d_in[0];
    const float* gt_boxes    = (const float*)d_in[1];
    const unsigned char* mask_gt = (const unsigned char*)d_in[2];
    const float* pred_scores = (const float*)d_in[3];
    const int*   gt_labels   = (const int*)d_in[4];

    float* out_final = (float*)d_out;
    float* out_cost  = out_final + (size_t)BS * G_N * A_N;

    // ws layout (256B-aligned chunks)
    size_t off = 0;
    auto alloc = [&](size_t bytes) {
        void* p = (char*)d_ws + off;
        off += (bytes + 255) & ~(size_t)255;
        return p;
    };
    unsigned long long* slot = (unsigned long long*)alloc((size_t)BS * A_N * 8);
    int*    topk_ws = (int*)   alloc((size_t)BS * G_N * TK * 4);
    float4* tb_box  = (float4*)alloc((size_t)BS * G_N * 16);
    float4* tb_mid  = (float4*)alloc((size_t)BS * G_N * 16);
    float4* tb_ctr  = (float4*)alloc((size_t)BS * G_N * 16);
    int*    tb_ord  = (int*)   alloc((size_t)BS * G_N * 4);
    int*    tb_rowk = (int*)   alloc((size_t)BS * G_N * 4);
    int*    tb_lab  = (int*)   alloc((size_t)BS * G_N * 4);
    int*    tb_rank = (int*)   alloc((size_t)BS * NC_N * 4);
    (void)off;  // ws_size observed ~500 MB >> 2.4 MB needed

    const long ns4 = (long)BS * A_N / 2;   // u64 pairs as uint4
    k_init <<<dim3(132), 256, 0, stream>>>((uint4*)slot, ns4);
    k_setup<<<dim3(BS), 128, 0, stream>>>(gt_boxes, gt_labels,
                                          tb_box, tb_mid, tb_ctr,
                                          tb_ord, tb_rowk, tb_lab, tb_rank);
    k_cost <<<dim3((A_N + 63) / 64, BS), 256, 0, stream>>>(
        pred_boxes, pred_scores, tb_box, tb_mid, tb_ctr,
        tb_ord, tb_rowk, tb_lab, tb_rank, out_cost);
    k_topk <<<dim3(BS * G_N), 256, 0, stream>>>(out_cost, mask_gt, topk_ws, slot);
    k_fin  <<<dim3((A_N / 4 + 255) / 256, BS), 256, 0, stream>>>(slot, out_final);
}